// Round 3
// baseline (106.246 us; speedup 1.0000x reference)
//
#include <hip/hip_runtime.h>

// OnlineAverager: sliding-window online mean.
// UPDATE=4096, BATCH=256, NUM_UPD=16, SNAPSHOT=65536, SNAP_LEN=1110016.
//
// Key identities:
//  - snap position p (block b=p>>12) is touched by steps i in [b-15, b] ∩ [0,255]
//  - the update element used at step i for position p is update_flat[p + i*61440]
//    (each update element read exactly once)
//  - norm weight at step i for position p is s+1 where s = i-(b-15)
//  - effective weight = min(s+1, idx0+i+1). For 15<=b<=255 and idx0>=0:
//    i = b-15+s is in [0,255] (no clamp needed), and
//    idx0+i+1 = idx0+(b-15)+s+1 >= s+1  → weight == s+1, a COMPILE-TIME
//    constant → reciprocal is a literal.
//    For b>255 (tail) or b<15 (ramp), steps must be clamped/masked — general path.
//  - d_out[p] = final snap[p] for p < SNAP_LEN; d_out[SNAP_LEN..2158592)=0;
//    d_out[2158592] = idx0+256.

#define UPDATE_SIZE   4096
#define BATCH         256
#define NUM_UPD       16
#define SNAPSHOT_SIZE (UPDATE_SIZE * NUM_UPD)           // 65536
#define OUT_SIZE      (UPDATE_SIZE * BATCH)             // 1048576
#define SNAP_LEN      (SNAPSHOT_SIZE + (BATCH - 1) * UPDATE_SIZE) // 1110016
#define STRIDE        (SNAPSHOT_SIZE - UPDATE_SIZE)     // 61440 floats

#define MAIN_T  (SNAP_LEN / 4)          // 277504 threads, one float4 each
#define ZERO_T  (OUT_SIZE / 4)          // 262144 threads zero-fill the tail
#define TOTAL_T (MAIN_T + ZERO_T)       // 539648 -> exactly 2108 blocks of 256

// clang-native vector: __builtin_nontemporal_* requires this, not float4.
typedef float f4 __attribute__((ext_vector_type(4)));

__global__ __launch_bounds__(256) void online_avg_kernel(
    const float* __restrict__ upd,      // (256, 65536) flat
    const float* __restrict__ snap_in,  // (SNAP_LEN,)
    const float* __restrict__ uidx,     // (1,)
    float* __restrict__ out) {          // (2158593,)
  const int t = blockIdx.x * 256 + threadIdx.x;

  if (t < MAIN_T) {
    const int p = t * 4;
    // b = t>>10 is wave-uniform: waves are 64-aligned in t, b flips every 1024.
    // readfirstlane forces it (and everything derived) into SGPRs, so the 16
    // stream bases become saddr-form global_load_dwordx4 with one voffset.
    const int b = __builtin_amdgcn_readfirstlane(t >> 10);   // 0..270
    const float idx0 = uidx[0];

    f4 acc = __builtin_nontemporal_load(
        reinterpret_cast<const f4*>(snap_in + p));

    if (b >= 15 && b <= 255 && idx0 >= 0.0f) {
      // Fast path (89% of waves): all 16 steps i=b-15+s lie in [0,255] —
      // loads are in-bounds unclamped, and the weight is exactly s+1 →
      // reciprocal is a compile-time literal. No divides, no selects.
      const f4* base =
          reinterpret_cast<const f4*>(upd + p + (b - 15) * STRIDE);
#pragma unroll
      for (int s = 0; s < 16; ++s) {
        const f4 x = __builtin_nontemporal_load(base + s * (STRIDE / 4));
        const float rw = 1.0f / (float)(s + 1);   // folded at compile time
        acc.x = fmaf(x.x - acc.x, rw, acc.x);
        acc.y = fmaf(x.y - acc.y, rw, acc.y);
        acc.z = fmaf(x.z - acc.z, rw, acc.z);
        acc.w = fmaf(x.w - acc.w, rw, acc.w);
      }
    } else {
      // General path: leading ramp (b<15), trailing tail (b>255), or
      // pathological idx0<0. Clamp keeps loads in-bounds
      // (max addr = p + 255*STRIDE + 4 <= 16777216 floats exactly);
      // rw=0 masks the invalid steps.
#pragma unroll
      for (int s = 0; s < 16; ++s) {
        const int i  = b - 15 + s;
        const int ic = min(max(i, 0), 255);
        const f4 x = *reinterpret_cast<const f4*>(upd + p + ic * STRIDE);
        const float w  = fminf((float)(s + 1), idx0 + (float)(i + 1));
        const float rw = (i == ic) ? __builtin_amdgcn_rcpf(w) : 0.0f;
        acc.x = fmaf(x.x - acc.x, rw, acc.x);
        acc.y = fmaf(x.y - acc.y, rw, acc.y);
        acc.z = fmaf(x.z - acc.z, rw, acc.z);
        acc.w = fmaf(x.w - acc.w, rw, acc.w);
      }
    }

    __builtin_nontemporal_store(acc, reinterpret_cast<f4*>(out + p));
    if (t == 0) out[OUT_SIZE + SNAP_LEN] = idx0 + (float)BATCH;  // update_idx
  } else if (t < TOTAL_T) {
    const int q = (t - MAIN_T) * 4;
    const f4 z = {0.0f, 0.0f, 0.0f, 0.0f};
    __builtin_nontemporal_store(z, reinterpret_cast<f4*>(out + SNAP_LEN + q));
  }
}

extern "C" void kernel_launch(void* const* d_in, const int* in_sizes, int n_in,
                              void* d_out, int out_size, void* d_ws, size_t ws_size,
                              hipStream_t stream) {
  const float* upd     = (const float*)d_in[0];
  const float* snap_in = (const float*)d_in[1];
  const float* uidx    = (const float*)d_in[2];
  float* out           = (float*)d_out;

  const int blocks = TOTAL_T / 256;     // 2108 exactly
  online_avg_kernel<<<blocks, 256, 0, stream>>>(upd, snap_in, uidx, out);
}

// Round 4
// 98.997 us; speedup vs baseline: 1.0732x; 1.0732x over previous
//
#include <hip/hip_runtime.h>

// OnlineAverager: sliding-window online mean.
// UPDATE=4096, BATCH=256, NUM_UPD=16, SNAPSHOT=65536, SNAP_LEN=1110016.
//
// Key identities:
//  - snap position p (block b=p>>12) is touched by steps i in [b-15, b] ∩ [0,255]
//  - the update element used at step i for position p is update_flat[p + i*61440]
//    (each update element read exactly once)
//  - norm weight at step i for position p is s+1 where s = i-(b-15)
//  - effective weight = min(s+1, idx0+i+1). For 15<=b<=255 and idx0>=0:
//    i = b-15+s is in [0,255] (no clamp needed), and
//    idx0+i+1 = idx0+(b-15)+s+1 >= s+1  → weight == s+1, a COMPILE-TIME
//    constant → reciprocal is a literal.
//    For b>255 (tail) or b<15 (ramp), steps must be clamped/masked.
//  - d_out[p] = final snap[p] for p < SNAP_LEN; d_out[SNAP_LEN..2158592)=0;
//    d_out[2158592] = idx0+256.
//
// NOTE (round-3 post-mortem): nontemporal hints on the streams REGRESSED the
// kernel ~14→22 µs. upd (67MB) persists across bench iterations and fits in
// the 256MB L3 — plain loads let repeat iterations hit L3 above HBM rate;
// nt marked those lines evict-first. Keep plain loads/stores.

#define UPDATE_SIZE   4096
#define BATCH         256
#define NUM_UPD       16
#define SNAPSHOT_SIZE (UPDATE_SIZE * NUM_UPD)           // 65536
#define OUT_SIZE      (UPDATE_SIZE * BATCH)             // 1048576
#define SNAP_LEN      (SNAPSHOT_SIZE + (BATCH - 1) * UPDATE_SIZE) // 1110016
#define STRIDE        (SNAPSHOT_SIZE - UPDATE_SIZE)     // 61440 floats

#define MAIN_T  (SNAP_LEN / 4)          // 277504 threads, one float4 each
#define ZERO_T  (OUT_SIZE / 4)          // 262144 threads zero-fill the tail
#define TOTAL_T (MAIN_T + ZERO_T)       // 539648 -> exactly 2108 blocks of 256

typedef float f4 __attribute__((ext_vector_type(4)));

__global__ __launch_bounds__(256) void online_avg_kernel(
    const float* __restrict__ upd,      // (256, 65536) flat
    const float* __restrict__ snap_in,  // (SNAP_LEN,)
    const float* __restrict__ uidx,     // (1,)
    float* __restrict__ out) {          // (2158593,)
  const int t = blockIdx.x * 256 + threadIdx.x;

  if (t < MAIN_T) {
    const int p = t * 4;
    // b = t>>10 is wave-uniform: waves are 64-aligned in t, b flips every 1024.
    // readfirstlane forces it into SGPRs so the 16 stream bases become
    // saddr-form global_load_dwordx4 with one shared voffset.
    const int b = __builtin_amdgcn_readfirstlane(t >> 10);   // 0..270
    const float idx0 = uidx[0];

    f4 acc = *reinterpret_cast<const f4*>(snap_in + p);

    if (b >= 15 && b <= 255 && idx0 >= 0.0f) {
      // Fast path (89% of waves): all 16 steps i=b-15+s lie in [0,255] —
      // loads in-bounds unclamped, weight exactly s+1 → reciprocal is a
      // compile-time literal. No divides, no selects.
      const f4* base =
          reinterpret_cast<const f4*>(upd + p + (b - 15) * STRIDE);
#pragma unroll
      for (int s = 0; s < 16; ++s) {
        const f4 x = base[s * (STRIDE / 4)];
        const float rw = 1.0f / (float)(s + 1);   // folded at compile time
        acc.x = fmaf(x.x - acc.x, rw, acc.x);
        acc.y = fmaf(x.y - acc.y, rw, acc.y);
        acc.z = fmaf(x.z - acc.z, rw, acc.z);
        acc.w = fmaf(x.w - acc.w, rw, acc.w);
      }
    } else {
      // General path: leading ramp (b<15), trailing tail (b>255), or
      // pathological idx0<0. Clamp keeps loads in-bounds
      // (max addr = p + 255*STRIDE + 4 <= 16777216 floats exactly);
      // rw=0 masks invalid steps.
#pragma unroll
      for (int s = 0; s < 16; ++s) {
        const int i  = b - 15 + s;
        const int ic = min(max(i, 0), 255);
        const f4 x = *reinterpret_cast<const f4*>(upd + p + ic * STRIDE);
        const float w  = fminf((float)(s + 1), idx0 + (float)(i + 1));
        const float rw = (i == ic) ? __builtin_amdgcn_rcpf(w) : 0.0f;
        acc.x = fmaf(x.x - acc.x, rw, acc.x);
        acc.y = fmaf(x.y - acc.y, rw, acc.y);
        acc.z = fmaf(x.z - acc.z, rw, acc.z);
        acc.w = fmaf(x.w - acc.w, rw, acc.w);
      }
    }

    *reinterpret_cast<f4*>(out + p) = acc;
    if (t == 0) out[OUT_SIZE + SNAP_LEN] = idx0 + (float)BATCH;  // update_idx
  } else if (t < TOTAL_T) {
    const int q = (t - MAIN_T) * 4;
    const f4 z = {0.0f, 0.0f, 0.0f, 0.0f};
    *reinterpret_cast<f4*>(out + SNAP_LEN + q) = z;
  }
}

extern "C" void kernel_launch(void* const* d_in, const int* in_sizes, int n_in,
                              void* d_out, int out_size, void* d_ws, size_t ws_size,
                              hipStream_t stream) {
  const float* upd     = (const float*)d_in[0];
  const float* snap_in = (const float*)d_in[1];
  const float* uidx    = (const float*)d_in[2];
  float* out           = (float*)d_out;

  const int blocks = TOTAL_T / 256;     // 2108 exactly
  online_avg_kernel<<<blocks, 256, 0, stream>>>(upd, snap_in, uidx, out);
}